// Round 2
// baseline (92.735 us; speedup 1.0000x reference)
//
#include <hip/hip_runtime.h>
#include <hip/hip_bf16.h>

// PairRE scoring: out[b,n] = -|| t_hat[n]*rt[b] - h_hat[b]*rh[b] ||_2
// B=512, N=2048, E=256.
//
// x(b,n) = dot([T^2 | T]_n , [rt^2 | -2*rt*Hh]_b) + c_b,
//   T = t/||t||, Hh = (h/||h||)*rh, c_b = ||Hh_b||^2.
// FULLY FUSED: one kernel, no workspace. Each block owns a 64(b) x 64(n)
// tile, recomputes norms for its rows (cheap, L2-resident re-reads),
// stages scaled bf16 K-chunks directly to LDS, MFMA-accumulates, -sqrt.

#define B_DIM 512
#define N_DIM 2048
#define E_DIM 256
#define K_DIM 512
#define KC    128       // K-chunk in LDS
#define LDP   136       // padded LDS row stride (ushorts)

typedef __attribute__((ext_vector_type(8))) __bf16 bf16x8;
typedef __attribute__((ext_vector_type(4))) float f32x4;

__device__ inline ushort f2bf(float x) {
    __hip_bfloat16 h = __float2bfloat16(x);   // RNE
    union { __hip_bfloat16 b; ushort u; } cv; cv.b = h; return cv.u;
}

__device__ inline float wave_sum(float v) {
#pragma unroll
    for (int m = 1; m < 64; m <<= 1) v += __shfl_xor(v, m, 64);
    return v;
}

__global__ __launch_bounds__(256) void pairre_fused(
        const float* __restrict__ head, const float* __restrict__ tail,
        const float* __restrict__ rel,  const int* __restrict__ rid,
        float* __restrict__ out) {
    __shared__ ushort Ts[64 * LDP];   // tail operand chunk  [T^2|T]
    __shared__ ushort As[64 * LDP];   // head operand chunk  [rt^2|-2*rt*Hh]
    __shared__ float inv_t[64];
    __shared__ float inv_h[64];
    __shared__ float cb_s[64];
    __shared__ int   rid_s[64];

    const int tid  = threadIdx.x;
    const int lane = tid & 63, wv = tid >> 6;
    const int n0 = blockIdx.x * 64;
    const int b0 = blockIdx.y * 64;

    // ---- phase 0: per-row norms (wave w owns rows w*16..w*16+15) ----
#pragma unroll 4
    for (int j = 0; j < 16; ++j) {
        const int r = wv * 16 + j;
        const float4 t4 = *(const float4*)(tail + (size_t)(n0 + r) * E_DIM + lane * 4);
        const float s = wave_sum(t4.x * t4.x + t4.y * t4.y + t4.z * t4.z + t4.w * t4.w);
        if (lane == 0) inv_t[r] = 1.0f / fmaxf(sqrtf(s), 1e-12f);
    }
#pragma unroll 4
    for (int j = 0; j < 16; ++j) {
        const int r = wv * 16 + j;
        const int id = rid[b0 + r];
        const float4 h4 = *(const float4*)(head + (size_t)(b0 + r) * E_DIM + lane * 4);
        const float4 rh4 = *(const float4*)(rel + (size_t)id * (2 * E_DIM) + lane * 4);
        const float p0 = h4.x * rh4.x, p1 = h4.y * rh4.y, p2 = h4.z * rh4.z, p3 = h4.w * rh4.w;
        float s1 = h4.x * h4.x + h4.y * h4.y + h4.z * h4.z + h4.w * h4.w;
        float s2 = p0 * p0 + p1 * p1 + p2 * p2 + p3 * p3;
        s1 = wave_sum(s1);
        s2 = wave_sum(s2);
        if (lane == 0) {
            const float inv = 1.0f / fmaxf(sqrtf(s1), 1e-12f);
            inv_h[r] = inv;
            cb_s[r]  = inv * inv * s2;
            rid_s[r] = id;
        }
    }
    __syncthreads();

    f32x4 acc[4];
#pragma unroll
    for (int i = 0; i < 4; ++i) acc[i] = f32x4{0.f, 0.f, 0.f, 0.f};

    const int ml = lane & 15, q = lane >> 4;

#pragma unroll
    for (int chunk = 0; chunk < K_DIM / KC; ++chunk) {
        const int k0 = chunk * KC;
        const bool sq = (k0 < E_DIM);         // squares region vs linear region
        const int kb = k0 & (E_DIM - 1);      // source column base within E
        if (chunk) __syncthreads();           // protect LDS vs prev MFMA reads

        // ---- stage 64 x KC of both operands (bf16) into LDS ----
        for (int i = tid; i < 64 * (KC / 4); i += 256) {
            const int row = i >> 5;           // 0..63
            const int col = (i & 31) * 4;     // 0..124
            const int srck = kb + col;
            // tail operand
            {
                const float4 t4 = *(const float4*)(tail + (size_t)(n0 + row) * E_DIM + srck);
                const float inv = inv_t[row];
                float v0 = t4.x * inv, v1 = t4.y * inv, v2 = t4.z * inv, v3 = t4.w * inv;
                if (sq) { v0 *= v0; v1 *= v1; v2 *= v2; v3 *= v3; }
                ushort4 u = { f2bf(v0), f2bf(v1), f2bf(v2), f2bf(v3) };
                *(ushort4*)&Ts[row * LDP + col] = u;
            }
            // head operand
            {
                const int id = rid_s[row];
                const float4 rt4 = *(const float4*)(rel + (size_t)id * (2 * E_DIM) + E_DIM + srck);
                float v0, v1, v2, v3;
                if (sq) {
                    v0 = rt4.x * rt4.x; v1 = rt4.y * rt4.y;
                    v2 = rt4.z * rt4.z; v3 = rt4.w * rt4.w;
                } else {
                    const float4 h4 = *(const float4*)(head + (size_t)(b0 + row) * E_DIM + srck);
                    const float4 rh4 = *(const float4*)(rel + (size_t)id * (2 * E_DIM) + srck);
                    const float inv = inv_h[row];
                    v0 = -2.f * rt4.x * (h4.x * inv * rh4.x);
                    v1 = -2.f * rt4.y * (h4.y * inv * rh4.y);
                    v2 = -2.f * rt4.z * (h4.z * inv * rh4.z);
                    v3 = -2.f * rt4.w * (h4.w * inv * rh4.w);
                }
                ushort4 u = { f2bf(v0), f2bf(v1), f2bf(v2), f2bf(v3) };
                *(ushort4*)&As[row * LDP + col] = u;
            }
        }
        __syncthreads();

        // ---- MFMA over this chunk ----
#pragma unroll
        for (int ks = 0; ks < KC / 32; ++ks) {
            const int k = ks * 32;
            const bf16x8 a = *reinterpret_cast<const bf16x8*>(
                &As[(wv * 16 + ml) * LDP + k + q * 8]);
#pragma unroll
            for (int nt = 0; nt < 4; ++nt) {
                const bf16x8 bb = *reinterpret_cast<const bf16x8*>(
                    &Ts[(nt * 16 + ml) * LDP + k + q * 8]);
                acc[nt] = __builtin_amdgcn_mfma_f32_16x16x32_bf16(a, bb, acc[nt], 0, 0, 0);
            }
        }
    }

    // ---- epilogue: x = acc + c_b ; out = -sqrt(max(x,0)) ----
    float cb[4];
#pragma unroll
    for (int r = 0; r < 4; ++r) cb[r] = cb_s[wv * 16 + q * 4 + r];
#pragma unroll
    for (int nt = 0; nt < 4; ++nt) {
        const int n_idx = n0 + nt * 16 + ml;
#pragma unroll
        for (int r = 0; r < 4; ++r) {
            const int b_idx = b0 + wv * 16 + q * 4 + r;
            const float x = acc[nt][r] + cb[r];
            out[(size_t)b_idx * N_DIM + n_idx] = -sqrtf(fmaxf(x, 0.f));
        }
    }
}

extern "C" void kernel_launch(void* const* d_in, const int* in_sizes, int n_in,
                              void* d_out, int out_size, void* d_ws, size_t ws_size,
                              hipStream_t stream) {
    const float* head = (const float*)d_in[0];
    const float* tail = (const float*)d_in[1];
    const float* rel  = (const float*)d_in[2];
    const int*   rid  = (const int*)d_in[3];
    float* out = (float*)d_out;

    dim3 grid(N_DIM / 64, B_DIM / 64);   // 32 x 8 = 256 blocks, 1/CU
    pairre_fused<<<grid, 256, 0, stream>>>(head, tail, rel, rid, out);
}

// Round 3
// 70.352 us; speedup vs baseline: 1.3182x; 1.3182x over previous
//
#include <hip/hip_runtime.h>
#include <hip/hip_bf16.h>

// PairRE scoring: out[b,n] = -|| t_hat[n]*rt[b] - h_hat[b]*rh[b] ||_2
// B=512, N=2048, E=256.
//
// x(b,n) = dot([T^2 | T]_n , [rt^2 | -2*rt*Hh]_b) + c_b,
//   T = t/||t||, Hh = (h/||h||)*rh, c_b = ||Hh_b||^2.
//
// R3 structure: prep writes bf16 operands in MFMA-FRAGMENT-PACKED layout
// (frag(group g, kstep s) = 64 lanes x 16B contiguous at (g*16+s)*1KB), so
// the score kernel runs with NO LDS and NO barriers: per-wave direct
// coalesced fragment loads from L2-resident operands + MFMA chain.
// Score: wave tile 16(b) x 32(n) -> 2048 independent waves (8/CU).

#define B_DIM 512
#define N_DIM 2048
#define E_DIM 256
#define K_DIM 512
#define NSTEP 16        // K/32 MFMA k-steps
#define FRAG_US 512     // ushorts per packed fragment (64 lanes * 8)

typedef __attribute__((ext_vector_type(8))) __bf16 bf16x8;
typedef __attribute__((ext_vector_type(4))) float f32x4;

__device__ inline ushort f2bf(float x) {
    __hip_bfloat16 h = __float2bfloat16(x);   // RNE
    union { __hip_bfloat16 b; ushort u; } cv; cv.b = h; return cv.u;
}

// sum across 256 threads, result broadcast to all. buf: float[4] LDS.
__device__ inline float block_reduce_sum_256(float v, float* buf) {
#pragma unroll
    for (int o = 32; o > 0; o >>= 1) v += __shfl_down(v, o, 64);
    const int lane = threadIdx.x & 63, wid = threadIdx.x >> 6;
    __syncthreads();
    if (lane == 0) buf[wid] = v;
    __syncthreads();
    return buf[0] + buf[1] + buf[2] + buf[3];
}

// ---------------- prep: packed-fragment bf16 operands + c_b ----------------
// blocks [0,2048): tail row n -> Tbig frags  value(k) = k<256 ? T[k]^2 : T[k-256]
// blocks [2048,2560): head row b -> Abig frags value(k) = k<256 ? rt[k]^2
//                                                   : -2*rt*Hh (e=k-256); cvec[b]
// Packed addr for row r=g*16+m, k=c*8+j (c=s*4+q):
//   dst = ((g*16+s)*64 + q*16 + m)*8 + j
__global__ __launch_bounds__(256) void prep_kernel(
        const float* __restrict__ head, const float* __restrict__ tail,
        const float* __restrict__ rel,  const int* __restrict__ rid,
        ushort* __restrict__ Tbig, ushort* __restrict__ Abig,
        float* __restrict__ cvec) {
    __shared__ float buf[4];
    const int tid = threadIdx.x;
    const int blk = blockIdx.x;
    if (blk < N_DIM) {
        const int n = blk;
        const float tv = tail[(size_t)n * E_DIM + tid];
        const float tot = block_reduce_sum_256(tv * tv, buf);
        const float inv = 1.0f / fmaxf(sqrtf(tot), 1e-12f);
        if (tid < 64) {
            const int c = tid, k0 = c * 8;
            const bool sqr = (k0 < E_DIM);
            const int e0 = sqr ? k0 : k0 - E_DIM;
            const float4 f0 = *(const float4*)(tail + (size_t)n * E_DIM + e0);
            const float4 f1 = *(const float4*)(tail + (size_t)n * E_DIM + e0 + 4);
            const float v[8] = {f0.x, f0.y, f0.z, f0.w, f1.x, f1.y, f1.z, f1.w};
            ushort u[8];
#pragma unroll
            for (int j = 0; j < 8; ++j) {
                float x = v[j] * inv;
                if (sqr) x *= x;
                u[j] = f2bf(x);
            }
            const int s = k0 >> 5, q = (k0 >> 3) & 3, g = n >> 4, m = n & 15;
            *(uint4*)(Tbig + (size_t)((g * 16 + s) * 64 + q * 16 + m) * 8) = *(const uint4*)u;
        }
    } else {
        const int b = blk - N_DIM;
        const int id = rid[b];
        const float hv = head[(size_t)b * E_DIM + tid];
        const float rh = rel[(size_t)id * (2 * E_DIM) + tid];
        const float s1 = block_reduce_sum_256(hv * hv, buf);
        const float inv = 1.0f / fmaxf(sqrtf(s1), 1e-12f);
        const float Hh = hv * inv * rh;
        const float s2 = block_reduce_sum_256(Hh * Hh, buf);
        if (tid == 0) cvec[b] = s2;
        if (tid < 64) {
            const int c = tid, k0 = c * 8;
            const bool sqr = (k0 < E_DIM);
            const int e0 = sqr ? k0 : k0 - E_DIM;
            const float4 rt0 = *(const float4*)(rel + (size_t)id * (2 * E_DIM) + E_DIM + e0);
            const float4 rt1 = *(const float4*)(rel + (size_t)id * (2 * E_DIM) + E_DIM + e0 + 4);
            const float rt[8] = {rt0.x, rt0.y, rt0.z, rt0.w, rt1.x, rt1.y, rt1.z, rt1.w};
            float v[8];
            if (sqr) {
#pragma unroll
                for (int j = 0; j < 8; ++j) v[j] = rt[j] * rt[j];
            } else {
                const float4 h0 = *(const float4*)(head + (size_t)b * E_DIM + e0);
                const float4 h1 = *(const float4*)(head + (size_t)b * E_DIM + e0 + 4);
                const float4 rh0 = *(const float4*)(rel + (size_t)id * (2 * E_DIM) + e0);
                const float4 rh1 = *(const float4*)(rel + (size_t)id * (2 * E_DIM) + e0 + 4);
                const float hh[8] = {h0.x, h0.y, h0.z, h0.w, h1.x, h1.y, h1.z, h1.w};
                const float rr[8] = {rh0.x, rh0.y, rh0.z, rh0.w, rh1.x, rh1.y, rh1.z, rh1.w};
#pragma unroll
                for (int j = 0; j < 8; ++j) v[j] = -2.0f * rt[j] * (hh[j] * inv * rr[j]);
            }
            ushort u[8];
#pragma unroll
            for (int j = 0; j < 8; ++j) u[j] = f2bf(v[j]);
            const int s = k0 >> 5, q = (k0 >> 3) & 3, g = b >> 4, m = b & 15;
            *(uint4*)(Abig + (size_t)((g * 16 + s) * 64 + q * 16 + m) * 8) = *(const uint4*)u;
        }
    }
}

// ---------------- score: no LDS, no barriers, direct frag loads ----------------
// 2048 waves; wave w: b-rows [p_b*16, +16), n-cols [p_n*32, +32).
// mfma(a=Abig frag (b rows), b=Tbig frag (n rows)): D col=lane&15 -> n,
// row=(lane>>4)*4+reg -> b.  (verified layout from R1 passing kernel)
__global__ __launch_bounds__(256) void score_kernel(
        const ushort* __restrict__ Tbig, const ushort* __restrict__ Abig,
        const float* __restrict__ cvec, float* __restrict__ out) {
    const int tid = threadIdx.x, lane = tid & 63, wv = tid >> 6;
    const int w = blockIdx.x * 4 + wv;
    const int p_b = w >> 6;          // 0..31
    const int p_n = w & 63;          // 0..63
    const int b0 = p_b * 16, n0 = p_n * 32;

    const ushort* Ab  = Abig + (size_t)(p_b * NSTEP) * FRAG_US + lane * 8;
    const ushort* Tb0 = Tbig + (size_t)(p_n * 2 * NSTEP) * FRAG_US + lane * 8;
    const ushort* Tb1 = Tb0 + (size_t)NSTEP * FRAG_US;

    f32x4 acc0 = {0.f, 0.f, 0.f, 0.f}, acc1 = {0.f, 0.f, 0.f, 0.f};

    bf16x8 a_c  = *(const bf16x8*)(Ab);
    bf16x8 b0_c = *(const bf16x8*)(Tb0);
    bf16x8 b1_c = *(const bf16x8*)(Tb1);
#pragma unroll
    for (int s = 0; s < NSTEP - 1; ++s) {
        const bf16x8 a_n  = *(const bf16x8*)(Ab  + (s + 1) * FRAG_US);
        const bf16x8 b0_n = *(const bf16x8*)(Tb0 + (s + 1) * FRAG_US);
        const bf16x8 b1_n = *(const bf16x8*)(Tb1 + (s + 1) * FRAG_US);
        acc0 = __builtin_amdgcn_mfma_f32_16x16x32_bf16(a_c, b0_c, acc0, 0, 0, 0);
        acc1 = __builtin_amdgcn_mfma_f32_16x16x32_bf16(a_c, b1_c, acc1, 0, 0, 0);
        a_c = a_n; b0_c = b0_n; b1_c = b1_n;
    }
    acc0 = __builtin_amdgcn_mfma_f32_16x16x32_bf16(a_c, b0_c, acc0, 0, 0, 0);
    acc1 = __builtin_amdgcn_mfma_f32_16x16x32_bf16(a_c, b1_c, acc1, 0, 0, 0);

    const int ml = lane & 15, q = lane >> 4;
#pragma unroll
    for (int r = 0; r < 4; ++r) {
        const int b = b0 + q * 4 + r;
        const float cb = cvec[b];
        out[(size_t)b * N_DIM + n0 + ml]      = -sqrtf(fmaxf(acc0[r] + cb, 0.f));
        out[(size_t)b * N_DIM + n0 + 16 + ml] = -sqrtf(fmaxf(acc1[r] + cb, 0.f));
    }
}

// ---------------- fallback (no workspace): pure fp32 ----------------
__global__ __launch_bounds__(256) void fallback_kernel(
        const float* __restrict__ head, const float* __restrict__ tail,
        const float* __restrict__ rel,  const int* __restrict__ rid,
        float* __restrict__ out) {
    __shared__ float Hh[E_DIM];
    __shared__ float RT[E_DIM];
    __shared__ float buf[4];
    const int b = blockIdx.x;
    const int tid = threadIdx.x;
    const float hv = head[(size_t)b * E_DIM + tid];
    const int id = rid[b];
    const float rh = rel[(size_t)id * (2 * E_DIM) + tid];
    const float rt = rel[(size_t)id * (2 * E_DIM) + E_DIM + tid];
    const float tot = block_reduce_sum_256(hv * hv, buf);
    const float inv = 1.0f / fmaxf(sqrtf(tot), 1e-12f);
    const float HhV = hv * inv * rh;
    Hh[tid] = HhV; RT[tid] = rt;
    const float c = block_reduce_sum_256(HhV * HhV, buf);
    __syncthreads();
    for (int n = tid; n < N_DIM; n += 256) {
        float S1 = 0.f, S2 = 0.f, Stt = 0.f;
        for (int e = 0; e < E_DIM; ++e) {
            const float tv = tail[(size_t)n * E_DIM + e];
            const float p = tv * RT[e];
            S1 += p * p; S2 += p * Hh[e]; Stt += tv * tv;
        }
        const float al = 1.0f / fmaxf(sqrtf(Stt), 1e-12f);
        const float x = al * al * S1 - 2.0f * al * S2 + c;
        out[(size_t)b * N_DIM + n] = -sqrtf(fmaxf(x, 0.f));
    }
}

extern "C" void kernel_launch(void* const* d_in, const int* in_sizes, int n_in,
                              void* d_out, int out_size, void* d_ws, size_t ws_size,
                              hipStream_t stream) {
    const float* head = (const float*)d_in[0];
    const float* tail = (const float*)d_in[1];
    const float* rel  = (const float*)d_in[2];
    const int*   rid  = (const int*)d_in[3];
    float* out = (float*)d_out;

    const size_t needT = (size_t)N_DIM * K_DIM * sizeof(ushort);   // 2 MB
    const size_t needA = (size_t)B_DIM * K_DIM * sizeof(ushort);   // 512 KB
    const size_t needC = (size_t)B_DIM * sizeof(float);            // 2 KB
    if (ws_size >= needT + needA + needC) {
        ushort* Tbig = (ushort*)d_ws;
        ushort* Abig = Tbig + (size_t)N_DIM * K_DIM;
        float*  cvec = (float*)(Abig + (size_t)B_DIM * K_DIM);
        prep_kernel<<<N_DIM + B_DIM, 256, 0, stream>>>(head, tail, rel, rid,
                                                       Tbig, Abig, cvec);
        score_kernel<<<B_DIM * N_DIM / (4 * 16 * 32), 256, 0, stream>>>(
            Tbig, Abig, cvec, out);   // 512 blocks, 2048 waves
    } else {
        fallback_kernel<<<B_DIM, 256, 0, stream>>>(head, tail, rel, rid, out);
    }
}

// Round 4
// 68.464 us; speedup vs baseline: 1.3545x; 1.0276x over previous
//
#include <hip/hip_runtime.h>
#include <hip/hip_bf16.h>

// PairRE scoring: out[b,n] = -|| t_hat[n]*rt[b] - h_hat[b]*rh[b] ||_2
// B=512, N=2048, E=256.
//
// x(b,n) = dot([T^2 | T]_n , [rt^2 | -2*rt*Hh]_b) + c_b,
//   T = t/||t||, Hh = (h/||h||)*rh, c_b = ||Hh_b||^2.
//
// R4: prep = barrier-free wave-per-row (640 blocks) writing bf16 operands in
// MFMA-fragment-packed layout; score = no-LDS no-barrier MFMA with 2x2 wave
// grid per block (A and T both L1-deduped) + XCD-locality block mapping
// (all blocks sharing T-groups have equal blockIdx.x -> same XCD L2).

#define B_DIM 512
#define N_DIM 2048
#define E_DIM 256
#define K_DIM 512
#define NSTEP 16        // K/32 MFMA k-steps
#define FRAG_US 512     // ushorts per packed fragment (64 lanes * 8)

typedef __attribute__((ext_vector_type(8))) __bf16 bf16x8;
typedef __attribute__((ext_vector_type(4))) float f32x4;

__device__ inline ushort f2bf(float x) {
    __hip_bfloat16 h = __float2bfloat16(x);   // RNE
    union { __hip_bfloat16 b; ushort u; } cv; cv.b = h; return cv.u;
}

__device__ inline float wave_sum(float v) {
#pragma unroll
    for (int m = 1; m < 64; m <<= 1) v += __shfl_xor(v, m, 64);
    return v;
}

// ---------------- prep: wave-per-row, packed-fragment bf16 operands ----------------
// Packed addr for row r=g*16+m, k=c*8+j (c=s*4+q): dst=((g*16+s)*64+q*16+m)*8
// Lane writes k0=lane*8 .. +7  ->  s=lane>>2, q=lane&3.
__global__ __launch_bounds__(256) void prep_kernel(
        const float* __restrict__ head, const float* __restrict__ tail,
        const float* __restrict__ rel,  const int* __restrict__ rid,
        ushort* __restrict__ Tbig, ushort* __restrict__ Abig,
        float* __restrict__ cvec) {
    const int tid = threadIdx.x, lane = tid & 63, wv = tid >> 6;
    const int w = blockIdx.x * 4 + wv;     // 0..2559
    const int s_ = lane >> 2, q = lane & 3;
    const int k0 = lane * 8;
    const bool sqr = (k0 < E_DIM);
    const int e0 = k0 & (E_DIM - 1);

    if (w < N_DIM) {
        const int n = w;
        const float* row = tail + (size_t)n * E_DIM;
        const float4 v4 = ((const float4*)row)[lane];
        const float s = wave_sum(v4.x * v4.x + v4.y * v4.y + v4.z * v4.z + v4.w * v4.w);
        const float inv = 1.0f / fmaxf(sqrtf(s), 1e-12f);
        const float4 f0 = *(const float4*)(row + e0);
        const float4 f1 = *(const float4*)(row + e0 + 4);
        const float v[8] = {f0.x, f0.y, f0.z, f0.w, f1.x, f1.y, f1.z, f1.w};
        ushort u[8];
#pragma unroll
        for (int j = 0; j < 8; ++j) {
            float x = v[j] * inv;
            if (sqr) x *= x;
            u[j] = f2bf(x);
        }
        const int g = n >> 4, m = n & 15;
        *(uint4*)(Tbig + (size_t)((g * 16 + s_) * 64 + q * 16 + m) * 8) = *(const uint4*)u;
    } else {
        const int b = w - N_DIM;
        const int id = rid[b];
        const float* hrow  = head + (size_t)b * E_DIM;
        const float* rhrow = rel + (size_t)id * (2 * E_DIM);
        const float* rtrow = rhrow + E_DIM;
        const float4 h4  = ((const float4*)hrow)[lane];
        const float4 rh4 = ((const float4*)rhrow)[lane];
        const float s1 = wave_sum(h4.x * h4.x + h4.y * h4.y + h4.z * h4.z + h4.w * h4.w);
        const float inv = 1.0f / fmaxf(sqrtf(s1), 1e-12f);
        const float p0 = h4.x * inv * rh4.x, p1 = h4.y * inv * rh4.y;
        const float p2 = h4.z * inv * rh4.z, p3 = h4.w * inv * rh4.w;
        const float s2 = wave_sum(p0 * p0 + p1 * p1 + p2 * p2 + p3 * p3);
        if (lane == 0) cvec[b] = s2;

        const float4 rt0 = *(const float4*)(rtrow + e0);
        const float4 rt1 = *(const float4*)(rtrow + e0 + 4);
        const float rt[8] = {rt0.x, rt0.y, rt0.z, rt0.w, rt1.x, rt1.y, rt1.z, rt1.w};
        float v[8];
        if (sqr) {
#pragma unroll
            for (int j = 0; j < 8; ++j) v[j] = rt[j] * rt[j];
        } else {
            const float4 h0 = *(const float4*)(hrow + e0);
            const float4 h1 = *(const float4*)(hrow + e0 + 4);
            const float4 r0 = *(const float4*)(rhrow + e0);
            const float4 r1 = *(const float4*)(rhrow + e0 + 4);
            const float hh[8] = {h0.x, h0.y, h0.z, h0.w, h1.x, h1.y, h1.z, h1.w};
            const float rr[8] = {r0.x, r0.y, r0.z, r0.w, r1.x, r1.y, r1.z, r1.w};
#pragma unroll
            for (int j = 0; j < 8; ++j) v[j] = -2.0f * rt[j] * (hh[j] * inv * rr[j]);
        }
        ushort u[8];
#pragma unroll
        for (int j = 0; j < 8; ++j) u[j] = f2bf(v[j]);
        const int g = b >> 4, m = b & 15;
        *(uint4*)(Abig + (size_t)((g * 16 + s_) * 64 + q * 16 + m) * 8) = *(const uint4*)u;
    }
}

// ---------------- score: no LDS/barriers; 2x2 wave grid per block ----------------
// grid = (32, 16): blockIdx.x = p_n (64 n-cols), blockIdx.y = b_super (32 b-rows).
// wave wv: A-group gA = b_super*2 + (wv&1); T-groups gT0 = p_n*4 + (wv>>1)*2, +1.
// Each A stream shared by waves {wv, wv^2}, each T stream by {wv, wv^1} -> L1 dedup.
// Linear block id = y*32+x -> XCD = x%8 (round-robin): all 16 blocks with equal
// p_n (sharing T) land on one XCD -> T L2-resident.
__global__ __launch_bounds__(256) void score_kernel(
        const ushort* __restrict__ Tbig, const ushort* __restrict__ Abig,
        const float* __restrict__ cvec, float* __restrict__ out) {
    const int tid = threadIdx.x, lane = tid & 63, wv = tid >> 6;
    const int p_n = blockIdx.x, b_super = blockIdx.y;
    const int gA  = b_super * 2 + (wv & 1);
    const int gT0 = p_n * 4 + (wv >> 1) * 2;

    const ushort* Ab  = Abig + (size_t)gA * NSTEP * FRAG_US + lane * 8;
    const ushort* Tb0 = Tbig + (size_t)gT0 * NSTEP * FRAG_US + lane * 8;
    const ushort* Tb1 = Tb0 + (size_t)NSTEP * FRAG_US;

    f32x4 acc0 = {0.f, 0.f, 0.f, 0.f}, acc1 = {0.f, 0.f, 0.f, 0.f};

    bf16x8 a_c  = *(const bf16x8*)(Ab);
    bf16x8 b0_c = *(const bf16x8*)(Tb0);
    bf16x8 b1_c = *(const bf16x8*)(Tb1);
#pragma unroll
    for (int s = 0; s < NSTEP - 1; ++s) {
        const bf16x8 a_n  = *(const bf16x8*)(Ab  + (s + 1) * FRAG_US);
        const bf16x8 b0_n = *(const bf16x8*)(Tb0 + (s + 1) * FRAG_US);
        const bf16x8 b1_n = *(const bf16x8*)(Tb1 + (s + 1) * FRAG_US);
        acc0 = __builtin_amdgcn_mfma_f32_16x16x32_bf16(a_c, b0_c, acc0, 0, 0, 0);
        acc1 = __builtin_amdgcn_mfma_f32_16x16x32_bf16(a_c, b1_c, acc1, 0, 0, 0);
        a_c = a_n; b0_c = b0_n; b1_c = b1_n;
    }
    acc0 = __builtin_amdgcn_mfma_f32_16x16x32_bf16(a_c, b0_c, acc0, 0, 0, 0);
    acc1 = __builtin_amdgcn_mfma_f32_16x16x32_bf16(a_c, b1_c, acc1, 0, 0, 0);

    const int ml = lane & 15, q = lane >> 4;
    const int b0 = gA * 16;
    const int n0 = gT0 * 16;
#pragma unroll
    for (int r = 0; r < 4; ++r) {
        const int b = b0 + q * 4 + r;
        const float cb = cvec[b];
        out[(size_t)b * N_DIM + n0 + ml]      = -sqrtf(fmaxf(acc0[r] + cb, 0.f));
        out[(size_t)b * N_DIM + n0 + 16 + ml] = -sqrtf(fmaxf(acc1[r] + cb, 0.f));
    }
}

// ---------------- fallback (no workspace): pure fp32 ----------------
__device__ inline float block_reduce_sum_256(float v, float* buf) {
#pragma unroll
    for (int o = 32; o > 0; o >>= 1) v += __shfl_down(v, o, 64);
    const int lane = threadIdx.x & 63, wid = threadIdx.x >> 6;
    __syncthreads();
    if (lane == 0) buf[wid] = v;
    __syncthreads();
    return buf[0] + buf[1] + buf[2] + buf[3];
}

__global__ __launch_bounds__(256) void fallback_kernel(
        const float* __restrict__ head, const float* __restrict__ tail,
        const float* __restrict__ rel,  const int* __restrict__ rid,
        float* __restrict__ out) {
    __shared__ float Hh[E_DIM];
    __shared__ float RT[E_DIM];
    __shared__ float buf[4];
    const int b = blockIdx.x;
    const int tid = threadIdx.x;
    const float hv = head[(size_t)b * E_DIM + tid];
    const int id = rid[b];
    const float rh = rel[(size_t)id * (2 * E_DIM) + tid];
    const float rt = rel[(size_t)id * (2 * E_DIM) + E_DIM + tid];
    const float tot = block_reduce_sum_256(hv * hv, buf);
    const float inv = 1.0f / fmaxf(sqrtf(tot), 1e-12f);
    const float HhV = hv * inv * rh;
    Hh[tid] = HhV; RT[tid] = rt;
    const float c = block_reduce_sum_256(HhV * HhV, buf);
    __syncthreads();
    for (int n = tid; n < N_DIM; n += 256) {
        float S1 = 0.f, S2 = 0.f, Stt = 0.f;
        for (int e = 0; e < E_DIM; ++e) {
            const float tv = tail[(size_t)n * E_DIM + e];
            const float p = tv * RT[e];
            S1 += p * p; S2 += p * Hh[e]; Stt += tv * tv;
        }
        const float al = 1.0f / fmaxf(sqrtf(Stt), 1e-12f);
        const float x = al * al * S1 - 2.0f * al * S2 + c;
        out[(size_t)b * N_DIM + n] = -sqrtf(fmaxf(x, 0.f));
    }
}

extern "C" void kernel_launch(void* const* d_in, const int* in_sizes, int n_in,
                              void* d_out, int out_size, void* d_ws, size_t ws_size,
                              hipStream_t stream) {
    const float* head = (const float*)d_in[0];
    const float* tail = (const float*)d_in[1];
    const float* rel  = (const float*)d_in[2];
    const int*   rid  = (const int*)d_in[3];
    float* out = (float*)d_out;

    const size_t needT = (size_t)N_DIM * K_DIM * sizeof(ushort);   // 2 MB
    const size_t needA = (size_t)B_DIM * K_DIM * sizeof(ushort);   // 512 KB
    const size_t needC = (size_t)B_DIM * sizeof(float);            // 2 KB
    if (ws_size >= needT + needA + needC) {
        ushort* Tbig = (ushort*)d_ws;
        ushort* Abig = Tbig + (size_t)N_DIM * K_DIM;
        float*  cvec = (float*)(Abig + (size_t)B_DIM * K_DIM);
        prep_kernel<<<(N_DIM + B_DIM) / 4, 256, 0, stream>>>(head, tail, rel, rid,
                                                             Tbig, Abig, cvec);
        dim3 grid(N_DIM / 64, B_DIM / 32);   // (32, 16) = 512 blocks
        score_kernel<<<grid, 256, 0, stream>>>(Tbig, Abig, cvec, out);
    } else {
        fallback_kernel<<<B_DIM, 256, 0, stream>>>(head, tail, rel, rid, out);
    }
}